// Round 1
// baseline (115.707 us; speedup 1.0000x reference)
//
#include <hip/hip_runtime.h>
#include <hip/hip_bf16.h>

// Volume-rendering composite:
//   dd = deltas * density                       [rays, 128]
//   T_i = exp(-sum_{j<i} dd_j)                  (exclusive cumsum)
//   w_i = (1 - exp(-dd_i)) * T_i = T_i - T_{i+1}
//   out[r, c] = sum_i w_i * rgb[r, i, c]        [rays, 3]
//
// One 64-lane wave per ray; lane L owns samples 2L and 2L+1 (contiguous
// float2 loads -> coalesced). Wave-level inclusive scan via __shfl_up,
// butterfly reduce via __shfl_down. Block = 256 threads = 4 rays.

__global__ __launch_bounds__(256) void composite_kernel(
    const float* __restrict__ rgb,      // [rays, 128, 3]
    const float* __restrict__ density,  // [rays, 128]
    const float* __restrict__ deltas,   // [rays, 128]
    float* __restrict__ out,            // [rays, 3]
    int num_rays)
{
    const int wave = threadIdx.x >> 6;           // 0..3
    const int lane = threadIdx.x & 63;
    const int ray  = blockIdx.x * 4 + wave;
    if (ray >= num_rays) return;

    // --- load density/deltas pair for this lane's 2 samples ---
    const float2* de2 = reinterpret_cast<const float2*>(density + (size_t)ray * 128);
    const float2* dl2 = reinterpret_cast<const float2*>(deltas  + (size_t)ray * 128);
    const float2 de = de2[lane];
    const float2 dl = dl2[lane];
    const float dd0 = de.x * dl.x;
    const float dd1 = de.y * dl.y;
    const float local = dd0 + dd1;

    // --- inclusive scan of per-lane pair sums across the 64-lane wave ---
    float s = local;
#pragma unroll
    for (int off = 1; off < 64; off <<= 1) {
        float v = __shfl_up(s, off, 64);
        if (lane >= off) s += v;
    }
    const float excl = s - local;     // sum of dd over samples < 2*lane
    const float c0   = excl + dd0;    // inclusive through sample 2L
    const float c1   = c0 + dd1;      // inclusive through sample 2L+1

    const float T0 = __expf(-excl);
    const float T1 = __expf(-c0);
    const float T2 = __expf(-c1);
    const float w0 = T0 - T1;
    const float w1 = T1 - T2;

    // --- rgb: row is 384 contiguous floats; lane L reads floats [6L, 6L+6) ---
    const float2* r2 = reinterpret_cast<const float2*>(rgb + (size_t)ray * 384);
    const float2 a = r2[lane * 3 + 0];   // (r0, g0)
    const float2 b = r2[lane * 3 + 1];   // (b0, r1)
    const float2 c = r2[lane * 3 + 2];   // (g1, b1)

    float rr = w0 * a.x + w1 * b.y;
    float gg = w0 * a.y + w1 * c.x;
    float bb = w0 * b.x + w1 * c.y;

    // --- wave reduce over 64 lanes ---
#pragma unroll
    for (int off = 32; off; off >>= 1) {
        rr += __shfl_down(rr, off, 64);
        gg += __shfl_down(gg, off, 64);
        bb += __shfl_down(bb, off, 64);
    }

    if (lane == 0) {
        float* o = out + (size_t)ray * 3;
        o[0] = rr;
        o[1] = gg;
        o[2] = bb;
    }
}

extern "C" void kernel_launch(void* const* d_in, const int* in_sizes, int n_in,
                              void* d_out, int out_size, void* d_ws, size_t ws_size,
                              hipStream_t stream) {
    const float* rgb     = (const float*)d_in[0];
    const float* density = (const float*)d_in[1];
    const float* deltas  = (const float*)d_in[2];
    float* out = (float*)d_out;

    const int num_rays = in_sizes[1] / 128;            // 262144
    const int rays_per_block = 4;                      // 4 waves x 64 lanes
    const int grid = (num_rays + rays_per_block - 1) / rays_per_block;

    composite_kernel<<<grid, 256, 0, stream>>>(rgb, density, deltas, out, num_rays);
}